// Round 1
// baseline (64.814 us; speedup 1.0000x reference)
//
#include <hip/hip_runtime.h>

// Problem constants (from reference): B=2048, L=128, V=30522, D=768.
#define BB 2048
#define LL 128
#define DD 768
#define NT 192          // 3 waves; each thread owns one float4 (192*4 = 768)
#define DV (DD / 4)     // 192 float4 per row

__global__ __launch_bounds__(NT) void masked_mean_pool_kernel(
    const int* __restrict__ ids,      // [B, L] int32
    const int* __restrict__ mask,     // [B, L] int32 (0/1, left-contiguous)
    const float* __restrict__ emb,    // [V, D] fp32
    float* __restrict__ out)          // [B, D] fp32
{
    const int b = blockIdx.x;
    const int t = threadIdx.x;

    __shared__ int s_ids[LL];
    __shared__ int s_part[2];

    // Stage ids for this batch row and count valid tokens.
    if (t < LL) {
        s_ids[t] = ids[b * LL + t];
        int m = mask[b * LL + t];
        unsigned long long bal = __ballot(m != 0);   // per-wave 64-bit ballot
        if ((t & 63) == 0) s_part[t >> 6] = __popcll(bal);
    }
    __syncthreads();

    const int cnt = s_part[0] + s_part[1];           // >= 1 per problem spec

    const float4* __restrict__ embv = reinterpret_cast<const float4*>(emb);

    float ax = 0.f, ay = 0.f, az = 0.f, aw = 0.f;

    int l = 0;
    // Unroll x8: 8 independent dwordx4 gathers in flight per thread.
    for (; l + 8 <= cnt; l += 8) {
        float4 r0 = embv[s_ids[l + 0] * DV + t];
        float4 r1 = embv[s_ids[l + 1] * DV + t];
        float4 r2 = embv[s_ids[l + 2] * DV + t];
        float4 r3 = embv[s_ids[l + 3] * DV + t];
        float4 r4 = embv[s_ids[l + 4] * DV + t];
        float4 r5 = embv[s_ids[l + 5] * DV + t];
        float4 r6 = embv[s_ids[l + 6] * DV + t];
        float4 r7 = embv[s_ids[l + 7] * DV + t];
        ax += r0.x + r1.x + r2.x + r3.x + r4.x + r5.x + r6.x + r7.x;
        ay += r0.y + r1.y + r2.y + r3.y + r4.y + r5.y + r6.y + r7.y;
        az += r0.z + r1.z + r2.z + r3.z + r4.z + r5.z + r6.z + r7.z;
        aw += r0.w + r1.w + r2.w + r3.w + r4.w + r5.w + r6.w + r7.w;
    }
    for (; l < cnt; ++l) {
        float4 r = embv[s_ids[l] * DV + t];
        ax += r.x; ay += r.y; az += r.z; aw += r.w;
    }

    const float inv = 1.0f / (float)cnt;
    float4 o;
    o.x = ax * inv; o.y = ay * inv; o.z = az * inv; o.w = aw * inv;
    reinterpret_cast<float4*>(out)[b * DV + t] = o;
}

extern "C" void kernel_launch(void* const* d_in, const int* in_sizes, int n_in,
                              void* d_out, int out_size, void* d_ws, size_t ws_size,
                              hipStream_t stream) {
    const int*   ids  = (const int*)d_in[0];    // tag_input_ids  [B, L] int32
    const int*   mask = (const int*)d_in[1];    // tag_attention_mask [B, L] int32
    const float* emb  = (const float*)d_in[2];  // emb_weight [V, D] fp32
    float*       out  = (float*)d_out;          // [B, D] fp32

    masked_mean_pool_kernel<<<BB, NT, 0, stream>>>(ids, mask, emb, out);
}